// Round 1
// baseline (790.407 us; speedup 1.0000x reference)
//
#include <hip/hip_runtime.h>

typedef float f32x4 __attribute__((ext_vector_type(4)));
typedef __bf16 bf16x8 __attribute__((ext_vector_type(8)));

constexpr int BATCH = 2;
constexpr int NNODE = 10000;
constexpr int NEDGE = 320000;
constexpr int D = 128;

// ---- workspace layout (bytes) ----
constexpr size_t WS_SUMS = 0;         // f32 [B*N*128]  = 10,240,000
constexpr size_t WS_CNT  = 10240000;  // u32 [B*N]      = 80,000
constexpr size_t WS_W1E  = 10320000;  // bf16 pack 12*8*64*8 = 98,304 B
constexpr size_t WS_W2E  = 10418304;  // bf16 pack  4*8*64*8 = 32,768 B
constexpr size_t WS_W1N  = 10451072;  // bf16 pack  8*8*64*8 = 65,536 B
constexpr size_t WS_W2N  = 10516608;  // bf16 pack  4*8*64*8 = 32,768 B

__device__ __forceinline__ f32x4 mfma16(bf16x8 a, bf16x8 b, f32x4 c) {
    return __builtin_amdgcn_mfma_f32_16x16x32_bf16(a, b, c, 0, 0, 0);
}
__device__ __forceinline__ __bf16 tobf(float x) { return (__bf16)x; }
__device__ __forceinline__ bf16x8 cvt8(float4 a, float4 b) {
    bf16x8 r;
    r[0]=tobf(a.x); r[1]=tobf(a.y); r[2]=tobf(a.z); r[3]=tobf(a.w);
    r[4]=tobf(b.x); r[5]=tobf(b.y); r[6]=tobf(b.z); r[7]=tobf(b.w);
    return r;
}
__device__ __forceinline__ bf16x8 cvt8s(float4 a, float4 b, float s) {
    bf16x8 r;
    r[0]=tobf(a.x*s); r[1]=tobf(a.y*s); r[2]=tobf(a.z*s); r[3]=tobf(a.w*s);
    r[4]=tobf(b.x*s); r[5]=tobf(b.y*s); r[6]=tobf(b.z*s); r[7]=tobf(b.w*s);
    return r;
}
__device__ __forceinline__ float silu(float x) {
    float t = __builtin_amdgcn_exp2f(x * -1.44269504f);
    return x * __builtin_amdgcn_rcpf(1.0f + t);
}

// ---- pack weights fp32 [K][128] -> bf16 fragment layout [kb][ct][lane][8] ----
__global__ void gnn_pack_kernel(const float* __restrict__ fe_w1, const float* __restrict__ fe_w2,
                                const float* __restrict__ fn_w1, const float* __restrict__ fn_w2,
                                ushort* __restrict__ w1e, ushort* __restrict__ w2e,
                                ushort* __restrict__ w1n, ushort* __restrict__ w2n) {
    int t = blockIdx.x * blockDim.x + threadIdx.x;
    const float* src; ushort* dst; int lt;
    if      (t <  6144) { src = fe_w1; dst = w1e; lt = t;         }
    else if (t <  8192) { src = fe_w2; dst = w2e; lt = t - 6144;  }
    else if (t < 12288) { src = fn_w1; dst = w1n; lt = t - 8192;  }
    else if (t < 14336) { src = fn_w2; dst = w2n; lt = t - 12288; }
    else return;
    int lane = lt & 63, ct = (lt >> 6) & 7, kb = lt >> 9;
    int n  = ct * 16 + (lane & 15);
    int k0 = kb * 32 + (lane >> 4) * 8;
    ushort tmp[8];
#pragma unroll
    for (int j = 0; j < 8; j++)
        tmp[j] = __builtin_bit_cast(ushort, tobf(src[(size_t)(k0 + j) * 128 + n]));
    uint4 pk;
    pk.x = tmp[0] | ((uint)tmp[1] << 16); pk.y = tmp[2] | ((uint)tmp[3] << 16);
    pk.z = tmp[4] | ((uint)tmp[5] << 16); pk.w = tmp[6] | ((uint)tmp[7] << 16);
    *(uint4*)(dst + (size_t)lt * 8) = pk;
}

// ---- per-receiver edge counts (includes invalid edges, clamped like reference) ----
__global__ void gnn_cnt_kernel(const int* __restrict__ edges, unsigned* __restrict__ cnt) {
    int t = blockIdx.x * blockDim.x + threadIdx.x;
    if (t >= BATCH * NEDGE) return;
    int er = edges[2 * t + 1];
    int b  = (t >= NEDGE) ? 1 : 0;
    int r  = min(max(er, 0), NNODE - 1);
    atomicAdd(&cnt[b * NNODE + r], 1u);
}

// ---- edge MLP + E_out + scatter-sum ----
__launch_bounds__(512, 2)
__global__ void gnn_edge_kernel(const float* __restrict__ V, const float* __restrict__ E,
                                const int* __restrict__ edges,
                                const float* __restrict__ b1, const float* __restrict__ b2,
                                const float* __restrict__ g, const float* __restrict__ beta,
                                const ushort* __restrict__ w1p, const ushort* __restrict__ w2p,
                                float* __restrict__ sums, float* __restrict__ E_out) {
    __shared__ __align__(16) ushort lds[(98304 + 32768) / 2];  // 96KB w1 pack + 8x4KB h slabs
    const int tid = threadIdx.x;
    const int wave = tid >> 6, lane = tid & 63;
    const int quad = lane >> 4, c16 = lane & 15;

    {   // stage w1 pack into LDS (once per block)
        const uint4* s4 = (const uint4*)w1p;
        uint4* d4 = (uint4*)lds;
#pragma unroll
        for (int i = 0; i < 12; i++) d4[tid + i * 512] = s4[tid + i * 512];
    }
    __syncthreads();

    float b1v[8], b2v[8], gv[8], bev[8];
#pragma unroll
    for (int ct = 0; ct < 8; ct++) {
        int cg = ct * 16 + c16;
        b1v[ct] = b1[cg]; b2v[ct] = b2[cg]; gv[ct] = g[cg]; bev[ct] = beta[cg];
    }
    ushort* hslab = lds + 49152 + wave * 2048;  // byte 98304 + wave*4096

    for (int tile = blockIdx.x; tile < (BATCH * NEDGE) / 256; tile += gridDim.x) {
        const int row0 = tile * 256;
        const int bb = (row0 >= NEDGE) ? 1 : 0;
        const int wr0 = row0 + wave * 32;

        const float* pA[2][3];
#pragma unroll
        for (int rt = 0; rt < 2; rt++) {
            int ge = wr0 + rt * 16 + c16;
            int es = edges[2 * ge], er = edges[2 * ge + 1];
            int s = min(max(es, 0), NNODE - 1), r = min(max(er, 0), NNODE - 1);
            pA[rt][0] = V + ((size_t)bb * NNODE + s) * D;
            pA[rt][1] = V + ((size_t)bb * NNODE + r) * D;
            pA[rt][2] = E + (size_t)ge * D;
        }

        f32x4 acc1[2][8];
        const f32x4 fz = {0.f, 0.f, 0.f, 0.f};
#pragma unroll
        for (int rt = 0; rt < 2; rt++)
#pragma unroll
            for (int ct = 0; ct < 8; ct++) acc1[rt][ct] = fz;

        // GEMM1: [32 rows x 384] @ w1 -> [32 x 128]
#pragma unroll
        for (int kb = 0; kb < 12; kb++) {
            const int part = kb >> 2;
            const int kloc = (kb & 3) * 32 + quad * 8;
            bf16x8 a[2];
#pragma unroll
            for (int rt = 0; rt < 2; rt++) {
                const float* p = pA[rt][part] + kloc;
                float4 x0 = *(const float4*)p;
                float4 x1 = *(const float4*)(p + 4);
                a[rt] = cvt8(x0, x1);
            }
#pragma unroll
            for (int ct = 0; ct < 8; ct++) {
                bf16x8 bf = ((const bf16x8*)lds)[(kb * 8 + ct) * 64 + lane];
                acc1[0][ct] = mfma16(a[0], bf, acc1[0][ct]);
                acc1[1][ct] = mfma16(a[1], bf, acc1[1][ct]);
            }
        }

#pragma unroll
        for (int rt = 0; rt < 2; rt++) {
            // h = silu(acc1 + b1) -> wave-private LDS slab (bf16, XOR-swizzled)
#pragma unroll
            for (int ct = 0; ct < 8; ct++)
#pragma unroll
                for (int i = 0; i < 4; i++) {
                    float x = acc1[rt][ct][i] + b1v[ct];
                    float h = silu(x);
                    int hrow = quad * 4 + i;
                    int boff = hrow * 256 + ((2 * (ct * 16 + c16)) ^ ((hrow & 7) << 4));
                    hslab[boff >> 1] = __builtin_bit_cast(ushort, tobf(h));
                }

            f32x4 acc2[8];
#pragma unroll
            for (int ct = 0; ct < 8; ct++) acc2[ct] = fz;

            // GEMM2: [16 x 128] @ w2 -> [16 x 128]
#pragma unroll
            for (int kb2 = 0; kb2 < 4; kb2++) {
                int boff = c16 * 256 + ((2 * (kb2 * 32 + quad * 8)) ^ ((c16 & 7) << 4));
                bf16x8 a2 = *(const bf16x8*)((const char*)hslab + boff);
#pragma unroll
                for (int ct = 0; ct < 8; ct++) {
                    bf16x8 bf = *(const bf16x8*)(w2p + ((size_t)((kb2 * 8 + ct) * 64 + lane)) * 8);
                    acc2[ct] = mfma16(a2, bf, acc2[ct]);
                }
            }

            // bias + LayerNorm stats (rows spread over 16-lane groups)
            float sm[4] = {0,0,0,0}, sq[4] = {0,0,0,0};
#pragma unroll
            for (int ct = 0; ct < 8; ct++)
#pragma unroll
                for (int i = 0; i < 4; i++) {
                    float y = acc2[ct][i] + b2v[ct];
                    acc2[ct][i] = y; sm[i] += y; sq[i] += y * y;
                }
#pragma unroll
            for (int m = 1; m < 16; m <<= 1)
#pragma unroll
                for (int i = 0; i < 4; i++) {
                    sm[i] += __shfl_xor(sm[i], m, 64);
                    sq[i] += __shfl_xor(sq[i], m, 64);
                }
            float mu[4], rstd[4];
#pragma unroll
            for (int i = 0; i < 4; i++) {
                mu[i] = sm[i] * (1.0f / 128.0f);
                float var = sq[i] * (1.0f / 128.0f) - mu[i] * mu[i];
                rstd[i] = __builtin_amdgcn_rsqf(var + 1e-5f);
            }

            size_t eb[4], sb[4]; bool val[4];
#pragma unroll
            for (int i = 0; i < 4; i++) {
                int geo = row0 + wave * 32 + rt * 16 + quad * 4 + i;
                int es = edges[2 * geo], er = edges[2 * geo + 1];
                val[i] = (es >= 0) && (er >= 0);
                int r = min(max(er, 0), NNODE - 1);
                eb[i] = (size_t)geo * D;
                sb[i] = ((size_t)bb * NNODE + r) * D;
            }
#pragma unroll
            for (int ct = 0; ct < 8; ct++) {
                int cg = ct * 16 + c16;
#pragma unroll
                for (int i = 0; i < 4; i++) {
                    float e = (acc2[ct][i] - mu[i]) * rstd[i] * gv[ct] + bev[ct];
                    e = val[i] ? e : 0.0f;
                    E_out[eb[i] + cg] = E[eb[i] + cg] + e;
                    if (val[i]) unsafeAtomicAdd(&sums[sb[i] + cg], e);
                }
            }
        }
    }
}

// ---- node MLP: concat[V, agg] -> v_new; V_out = V + v_new ----
__launch_bounds__(512, 2)
__global__ void gnn_node_kernel(const float* __restrict__ V,
                                const float* __restrict__ sums, const unsigned* __restrict__ cnt,
                                const float* __restrict__ b1, const float* __restrict__ b2,
                                const float* __restrict__ g, const float* __restrict__ beta,
                                const ushort* __restrict__ w1p, const ushort* __restrict__ w2p,
                                float* __restrict__ V_out) {
    __shared__ __align__(16) ushort lds[(65536 + 32768) / 2];  // 64KB w1n pack + 8x4KB h slabs
    const int tid = threadIdx.x;
    const int wave = tid >> 6, lane = tid & 63;
    const int quad = lane >> 4, c16 = lane & 15;
    const int TOT = BATCH * NNODE;

    {
        const uint4* s4 = (const uint4*)w1p;
        uint4* d4 = (uint4*)lds;
#pragma unroll
        for (int i = 0; i < 8; i++) d4[tid + i * 512] = s4[tid + i * 512];
    }
    __syncthreads();

    float b1v[8], b2v[8], gv[8], bev[8];
#pragma unroll
    for (int ct = 0; ct < 8; ct++) {
        int cg = ct * 16 + c16;
        b1v[ct] = b1[cg]; b2v[ct] = b2[cg]; gv[ct] = g[cg]; bev[ct] = beta[cg];
    }
    ushort* hslab = lds + 32768 + wave * 2048;

    for (int tile = blockIdx.x; tile * 256 < TOT; tile += gridDim.x) {
        const int row0 = tile * 256;
        const int wr0 = row0 + wave * 32;

        const float* pV[2]; const float* pG[2]; float rinv[2];
#pragma unroll
        for (int rt = 0; rt < 2; rt++) {
            int grow = wr0 + rt * 16 + c16;
            int gc = min(grow, TOT - 1);
            pV[rt] = V    + (size_t)gc * D;
            pG[rt] = sums + (size_t)gc * D;
            rinv[rt] = __builtin_amdgcn_rcpf(fmaxf((float)cnt[gc], 1.0f));
        }

        f32x4 acc1[2][8];
        const f32x4 fz = {0.f, 0.f, 0.f, 0.f};
#pragma unroll
        for (int rt = 0; rt < 2; rt++)
#pragma unroll
            for (int ct = 0; ct < 8; ct++) acc1[rt][ct] = fz;

#pragma unroll
        for (int kb = 0; kb < 8; kb++) {
            const int part = kb >> 2;
            const int kloc = (kb & 3) * 32 + quad * 8;
            bf16x8 a[2];
#pragma unroll
            for (int rt = 0; rt < 2; rt++) {
                const float* p = (part == 0 ? pV[rt] : pG[rt]) + kloc;
                float4 x0 = *(const float4*)p;
                float4 x1 = *(const float4*)(p + 4);
                a[rt] = (part == 0) ? cvt8(x0, x1) : cvt8s(x0, x1, rinv[rt]);
            }
#pragma unroll
            for (int ct = 0; ct < 8; ct++) {
                bf16x8 bf = ((const bf16x8*)lds)[(kb * 8 + ct) * 64 + lane];
                acc1[0][ct] = mfma16(a[0], bf, acc1[0][ct]);
                acc1[1][ct] = mfma16(a[1], bf, acc1[1][ct]);
            }
        }

#pragma unroll
        for (int rt = 0; rt < 2; rt++) {
#pragma unroll
            for (int ct = 0; ct < 8; ct++)
#pragma unroll
                for (int i = 0; i < 4; i++) {
                    float x = acc1[rt][ct][i] + b1v[ct];
                    float h = silu(x);
                    int hrow = quad * 4 + i;
                    int boff = hrow * 256 + ((2 * (ct * 16 + c16)) ^ ((hrow & 7) << 4));
                    hslab[boff >> 1] = __builtin_bit_cast(ushort, tobf(h));
                }

            f32x4 acc2[8];
#pragma unroll
            for (int ct = 0; ct < 8; ct++) acc2[ct] = fz;
#pragma unroll
            for (int kb2 = 0; kb2 < 4; kb2++) {
                int boff = c16 * 256 + ((2 * (kb2 * 32 + quad * 8)) ^ ((c16 & 7) << 4));
                bf16x8 a2 = *(const bf16x8*)((const char*)hslab + boff);
#pragma unroll
                for (int ct = 0; ct < 8; ct++) {
                    bf16x8 bf = *(const bf16x8*)(w2p + ((size_t)((kb2 * 8 + ct) * 64 + lane)) * 8);
                    acc2[ct] = mfma16(a2, bf, acc2[ct]);
                }
            }

            float sm[4] = {0,0,0,0}, sq[4] = {0,0,0,0};
#pragma unroll
            for (int ct = 0; ct < 8; ct++)
#pragma unroll
                for (int i = 0; i < 4; i++) {
                    float y = acc2[ct][i] + b2v[ct];
                    acc2[ct][i] = y; sm[i] += y; sq[i] += y * y;
                }
#pragma unroll
            for (int m = 1; m < 16; m <<= 1)
#pragma unroll
                for (int i = 0; i < 4; i++) {
                    sm[i] += __shfl_xor(sm[i], m, 64);
                    sq[i] += __shfl_xor(sq[i], m, 64);
                }
            float mu[4], rstd[4];
#pragma unroll
            for (int i = 0; i < 4; i++) {
                mu[i] = sm[i] * (1.0f / 128.0f);
                float var = sq[i] * (1.0f / 128.0f) - mu[i] * mu[i];
                rstd[i] = __builtin_amdgcn_rsqf(var + 1e-5f);
            }
#pragma unroll
            for (int ct = 0; ct < 8; ct++) {
                int cg = ct * 16 + c16;
#pragma unroll
                for (int i = 0; i < 4; i++) {
                    int geo = row0 + wave * 32 + rt * 16 + quad * 4 + i;
                    if (geo < TOT) {
                        float vn = (acc2[ct][i] - mu[i]) * rstd[i] * gv[ct] + bev[ct];
                        V_out[(size_t)geo * D + cg] = V[(size_t)geo * D + cg] + vn;
                    }
                }
            }
        }
    }
}

extern "C" void kernel_launch(void* const* d_in, const int* in_sizes, int n_in,
                              void* d_out, int out_size, void* d_ws, size_t ws_size,
                              hipStream_t stream) {
    const float* V     = (const float*)d_in[0];
    const float* E     = (const float*)d_in[1];
    const int*   edges = (const int*)d_in[2];
    const float* fe_w1 = (const float*)d_in[3];
    const float* fe_b1 = (const float*)d_in[4];
    const float* fe_w2 = (const float*)d_in[5];
    const float* fe_b2 = (const float*)d_in[6];
    const float* fe_g  = (const float*)d_in[7];
    const float* fe_be = (const float*)d_in[8];
    const float* fn_w1 = (const float*)d_in[9];
    const float* fn_b1 = (const float*)d_in[10];
    const float* fn_w2 = (const float*)d_in[11];
    const float* fn_b2 = (const float*)d_in[12];
    const float* fn_g  = (const float*)d_in[13];
    const float* fn_be = (const float*)d_in[14];

    char* ws = (char*)d_ws;
    float*    sums = (float*)(ws + WS_SUMS);
    unsigned* cnt  = (unsigned*)(ws + WS_CNT);
    ushort*   w1e  = (ushort*)(ws + WS_W1E);
    ushort*   w2e  = (ushort*)(ws + WS_W2E);
    ushort*   w1n  = (ushort*)(ws + WS_W1N);
    ushort*   w2n  = (ushort*)(ws + WS_W2N);

    float* V_out = (float*)d_out;
    float* E_out = V_out + (size_t)BATCH * NNODE * D;

    hipMemsetAsync(d_ws, 0, WS_W1E, stream);  // zero sums + cnt
    gnn_pack_kernel<<<28, 512, 0, stream>>>(fe_w1, fe_w2, fn_w1, fn_w2, w1e, w2e, w1n, w2n);
    gnn_cnt_kernel<<<(BATCH * NEDGE) / 512, 512, 0, stream>>>(edges, cnt);
    gnn_edge_kernel<<<256, 512, 0, stream>>>(V, E, edges, fe_b1, fe_b2, fe_g, fe_be,
                                             w1e, w2e, sums, E_out);
    gnn_node_kernel<<<79, 512, 0, stream>>>(V, sums, cnt, fn_b1, fn_b2, fn_g, fn_be,
                                            w1n, w2n, V_out);
}